// Round 1
// baseline (305.126 us; speedup 1.0000x reference)
//
#include <hip/hip_runtime.h>
#include <hip/hip_bf16.h>

// GPT-2 attention: B=2, S=2048, D=1024, H=16, HS=64
// Pipeline: cvt(x)->bf16 ; transpose(w_qkv), transpose(w_proj) -> [N][K] bf16 ;
//           GEMM1 (qkv proj, scatter Q/K/V per-head, Q scaled, V transposed) ;
//           flash attention (causal, online softmax) ;
//           GEMM2 (out proj, +bias, fp32 out).

#define Bb 2
#define Ss 2048
#define Dd 1024
#define Hh 16
#define HSs 64

typedef __bf16 bf16x8 __attribute__((ext_vector_type(8)));
typedef float  f32x4  __attribute__((ext_vector_type(4)));

__device__ __forceinline__ unsigned short f2bf(float f) {
  unsigned int u = __float_as_uint(f);
  unsigned int lsb = (u >> 16) & 1u;
  u += 0x7fffu + lsb;               // round-to-nearest-even (finite values)
  return (unsigned short)(u >> 16);
}

__device__ __forceinline__ void async16(const unsigned short* g, unsigned short* l) {
  __builtin_amdgcn_global_load_lds(
      (const __attribute__((address_space(1))) unsigned int*)g,
      (__attribute__((address_space(3))) unsigned int*)l,
      16, 0, 0);
}

// ---------------------------------------------------------------- cvt x -> bf16
__global__ __launch_bounds__(256) void k_cvt_bf16(const float* __restrict__ in,
                                                  unsigned short* __restrict__ out,
                                                  int n) {
  int i = (blockIdx.x * 256 + threadIdx.x) * 4;
  int stride = gridDim.x * 256 * 4;
  for (; i < n; i += stride) {
    float4 v = *reinterpret_cast<const float4*>(in + i);
    ushort4 o;
    o.x = f2bf(v.x); o.y = f2bf(v.y); o.z = f2bf(v.z); o.w = f2bf(v.w);
    *reinterpret_cast<ushort4*>(out + i) = o;
  }
}

// ------------------------------------------------- transpose f32 [R][C] -> bf16 [C][R]
__global__ __launch_bounds__(256) void k_transpose_bf16(const float* __restrict__ in,
                                                        unsigned short* __restrict__ out,
                                                        int R, int C) {
  __shared__ float t[32][33];
  int c0 = blockIdx.x * 32, r0 = blockIdx.y * 32;
  int tx = threadIdx.x, ty = threadIdx.y;  // block (32,8)
  #pragma unroll
  for (int i = 0; i < 32; i += 8)
    t[ty + i][tx] = in[(size_t)(r0 + ty + i) * C + (c0 + tx)];
  __syncthreads();
  #pragma unroll
  for (int i = 0; i < 32; i += 8)
    out[(size_t)(c0 + ty + i) * R + (r0 + tx)] = f2bf(t[tx][ty + i]);
}

// ---------------------------------------------------------------- GEMM1: QKV proj
// A = xb [4096][1024] bf16, Bt = wqkvT [3072][1024] bf16, bias [3072] f32
// epilogue scatters: t=0 -> Qg[bh][s][c] * 0.125 ; t=1 -> Kg[bh][s][c] ; t=2 -> Vt[bh][c][s]
__global__ __launch_bounds__(256) void k_gemm_qkv(const unsigned short* __restrict__ A,
                                                  const unsigned short* __restrict__ Bt,
                                                  const float* __restrict__ bias,
                                                  unsigned short* __restrict__ Qg,
                                                  unsigned short* __restrict__ Kg,
                                                  unsigned short* __restrict__ Vt) {
  __shared__ unsigned short As[128 * 64];
  __shared__ unsigned short Bs[128 * 64];
  const int K = 1024;
  int bid = blockIdx.x;
  int tm = bid / 24, tn = bid % 24;
  int m0 = tm * 128, n0 = tn * 128;
  int tid = threadIdx.x;
  int w = tid >> 6, l = tid & 63;
  int lr = l & 15, lg = l >> 4;
  int wm = (w >> 1) * 64, wn = (w & 1) * 64;
  int srow = l >> 3, scol = (l & 7) * 8;

  f32x4 acc[4][4];
  #pragma unroll
  for (int i = 0; i < 4; ++i)
    #pragma unroll
    for (int j = 0; j < 4; ++j)
      acc[i][j] = (f32x4){0.f, 0.f, 0.f, 0.f};

  for (int k0 = 0; k0 < K; k0 += 64) {
    #pragma unroll
    for (int c = 0; c < 4; ++c) {
      int chunk = w * 4 + c;
      int row = chunk * 8 + srow;
      async16(&A[(size_t)(m0 + row) * K + k0 + scol], &As[chunk * 512]);
      async16(&Bt[(size_t)(n0 + row) * K + k0 + scol], &Bs[chunk * 512]);
    }
    __syncthreads();
    #pragma unroll
    for (int kk = 0; kk < 64; kk += 32) {
      bf16x8 af[4], bfr[4];
      #pragma unroll
      for (int mf = 0; mf < 4; ++mf)
        af[mf] = *reinterpret_cast<const bf16x8*>(&As[(wm + mf * 16 + lr) * 64 + kk + lg * 8]);
      #pragma unroll
      for (int nf = 0; nf < 4; ++nf)
        bfr[nf] = *reinterpret_cast<const bf16x8*>(&Bs[(wn + nf * 16 + lr) * 64 + kk + lg * 8]);
      #pragma unroll
      for (int mf = 0; mf < 4; ++mf)
        #pragma unroll
        for (int nf = 0; nf < 4; ++nf)
          acc[mf][nf] = __builtin_amdgcn_mfma_f32_16x16x32_bf16(af[mf], bfr[nf], acc[mf][nf], 0, 0, 0);
    }
    __syncthreads();
  }

  // n0..n0+127 lies within a single t segment (segments are 1024 wide) -> uniform branch
  #pragma unroll
  for (int mf = 0; mf < 4; ++mf) {
    #pragma unroll
    for (int nf = 0; nf < 4; ++nf) {
      int n = n0 + wn + nf * 16 + lr;
      int t = n >> 10, r = n & 1023;
      int h = r >> 6, cc = r & 63;
      float bv = bias[n];
      if (t == 2) {
        int m = m0 + wm + mf * 16 + lg * 4;
        int b = m >> 11, s = m & 2047;
        ushort4 pk;
        pk.x = f2bf(acc[mf][nf][0] + bv);
        pk.y = f2bf(acc[mf][nf][1] + bv);
        pk.z = f2bf(acc[mf][nf][2] + bv);
        pk.w = f2bf(acc[mf][nf][3] + bv);
        *reinterpret_cast<ushort4*>(&Vt[((size_t)(b * Hh + h) * HSs + cc) * Ss + s]) = pk;
      } else {
        #pragma unroll
        for (int j = 0; j < 4; ++j) {
          int m = m0 + wm + mf * 16 + lg * 4 + j;
          int b = m >> 11, s = m & 2047;
          size_t idx = ((size_t)(b * Hh + h) * Ss + s) * HSs + cc;
          float v = acc[mf][nf][j] + bv;
          if (t == 0) Qg[idx] = f2bf(v * 0.125f);
          else        Kg[idx] = f2bf(v);
        }
      }
    }
  }
}

// ---------------------------------------------------------------- flash attention
// grid 512: bid = bh*16 + qt.  Block: 4 waves, each wave 32 q rows. KV tiles of 64.
__global__ __launch_bounds__(256) void k_attn(const unsigned short* __restrict__ Qg,
                                              const unsigned short* __restrict__ Kg,
                                              const unsigned short* __restrict__ Vt,
                                              unsigned short* __restrict__ Ob) {
  __shared__ unsigned short Ks[64 * 64];
  __shared__ unsigned short Vs[64 * 64];
  __shared__ unsigned short Ps[4][32 * 72];  // per-wave P, padded rows (72) to break banks

  int bid = blockIdx.x;
  int qt = bid & 15;
  int bh = bid >> 4;
  int b = bh >> 4, h = bh & 15;
  int qs0 = qt * 128;

  int tid = threadIdx.x;
  int w = tid >> 6, l = tid & 63;
  int lr = l & 15, lg = l >> 4;
  int qw = qs0 + w * 32;
  int srow = l >> 3, scol = (l & 7) * 8;

  // Q fragments in registers: rows qw+mf*16+lr, cols kx*32 + lg*8
  bf16x8 qf[2][2];
  #pragma unroll
  for (int mf = 0; mf < 2; ++mf)
    #pragma unroll
    for (int kx = 0; kx < 2; ++kx)
      qf[mf][kx] = *reinterpret_cast<const bf16x8*>(
          &Qg[((size_t)bh * Ss + qw + mf * 16 + lr) * HSs + kx * 32 + lg * 8]);

  f32x4 oacc[2][4];
  #pragma unroll
  for (int mf = 0; mf < 2; ++mf)
    #pragma unroll
    for (int nf = 0; nf < 4; ++nf)
      oacc[mf][nf] = (f32x4){0.f, 0.f, 0.f, 0.f};
  float mrun[2][4], lrun[2][4];
  #pragma unroll
  for (int mf = 0; mf < 2; ++mf)
    #pragma unroll
    for (int j = 0; j < 4; ++j) { mrun[mf][j] = -1e30f; lrun[mf][j] = 0.f; }

  int ntiles = qt * 2 + 2;
  for (int t = 0; t < ntiles; ++t) {
    #pragma unroll
    for (int cch = 0; cch < 2; ++cch) {
      int chunk = w * 2 + cch;
      int row = chunk * 8 + srow;
      async16(&Kg[((size_t)bh * Ss + t * 64 + row) * HSs + scol], &Ks[chunk * 512]);
      async16(&Vt[((size_t)bh * HSs + row) * Ss + t * 64 + scol], &Vs[chunk * 512]);
    }
    __syncthreads();

    if (t * 64 <= qw + 31) {  // wave has at least one unmasked row in this tile
      f32x4 sacc[2][4];
      #pragma unroll
      for (int mf = 0; mf < 2; ++mf)
        #pragma unroll
        for (int nf = 0; nf < 4; ++nf)
          sacc[mf][nf] = (f32x4){0.f, 0.f, 0.f, 0.f};

      #pragma unroll
      for (int kx = 0; kx < 2; ++kx) {
        bf16x8 kf[4];
        #pragma unroll
        for (int nf = 0; nf < 4; ++nf)
          kf[nf] = *reinterpret_cast<const bf16x8*>(&Ks[(nf * 16 + lr) * 64 + kx * 32 + lg * 8]);
        #pragma unroll
        for (int mf = 0; mf < 2; ++mf)
          #pragma unroll
          for (int nf = 0; nf < 4; ++nf)
            sacc[mf][nf] = __builtin_amdgcn_mfma_f32_16x16x32_bf16(qf[mf][kx], kf[nf], sacc[mf][nf], 0, 0, 0);
      }

      if (t * 64 + 63 > qw) {  // diagonal region: causal mask
        #pragma unroll
        for (int mf = 0; mf < 2; ++mf)
          #pragma unroll
          for (int nf = 0; nf < 4; ++nf) {
            int kg = t * 64 + nf * 16 + lr;
            #pragma unroll
            for (int j = 0; j < 4; ++j) {
              int qg = qw + mf * 16 + lg * 4 + j;
              if (kg > qg) sacc[mf][nf][j] = -1e30f;
            }
          }
      }

      // online softmax (rows live in C layout: row=(lg*4+j), cols spread over 16-lane group)
      #pragma unroll
      for (int mf = 0; mf < 2; ++mf) {
        #pragma unroll
        for (int j = 0; j < 4; ++j) {
          float rmax = fmaxf(fmaxf(sacc[mf][0][j], sacc[mf][1][j]),
                             fmaxf(sacc[mf][2][j], sacc[mf][3][j]));
          #pragma unroll
          for (int d = 1; d < 16; d <<= 1)
            rmax = fmaxf(rmax, __shfl_xor(rmax, d));
          float mnew = fmaxf(mrun[mf][j], rmax);
          float cf = __expf(mrun[mf][j] - mnew);
          mrun[mf][j] = mnew;
          float psum = 0.f;
          #pragma unroll
          for (int nf = 0; nf < 4; ++nf) {
            float p = __expf(sacc[mf][nf][j] - mnew);
            sacc[mf][nf][j] = p;
            psum += p;
          }
          #pragma unroll
          for (int d = 1; d < 16; d <<= 1)
            psum += __shfl_xor(psum, d);
          lrun[mf][j] = lrun[mf][j] * cf + psum;
          #pragma unroll
          for (int nf = 0; nf < 4; ++nf)
            oacc[mf][nf][j] *= cf;
        }
      }

      // P -> LDS (bf16), per-wave private buffer
      #pragma unroll
      for (int mf = 0; mf < 2; ++mf)
        #pragma unroll
        for (int nf = 0; nf < 4; ++nf)
          #pragma unroll
          for (int j = 0; j < 4; ++j)
            Ps[w][(mf * 16 + lg * 4 + j) * 72 + nf * 16 + lr] = f2bf(sacc[mf][nf][j]);

      // PV
      #pragma unroll
      for (int kx = 0; kx < 2; ++kx) {
        bf16x8 pf[2], vf[4];
        #pragma unroll
        for (int mf = 0; mf < 2; ++mf)
          pf[mf] = *reinterpret_cast<const bf16x8*>(&Ps[w][(mf * 16 + lr) * 72 + kx * 32 + lg * 8]);
        #pragma unroll
        for (int nf = 0; nf < 4; ++nf)
          vf[nf] = *reinterpret_cast<const bf16x8*>(&Vs[(nf * 16 + lr) * 64 + kx * 32 + lg * 8]);
        #pragma unroll
        for (int mf = 0; mf < 2; ++mf)
          #pragma unroll
          for (int nf = 0; nf < 4; ++nf)
            oacc[mf][nf] = __builtin_amdgcn_mfma_f32_16x16x32_bf16(pf[mf], vf[nf], oacc[mf][nf], 0, 0, 0);
      }
    }
    __syncthreads();
  }

  // write attn output [b][s][h][c] bf16
  #pragma unroll
  for (int mf = 0; mf < 2; ++mf)
    #pragma unroll
    for (int nf = 0; nf < 4; ++nf)
      #pragma unroll
      for (int j = 0; j < 4; ++j) {
        int s = qw + mf * 16 + lg * 4 + j;
        int c = nf * 16 + lr;
        float v = oacc[mf][nf][j] / lrun[mf][j];
        Ob[((size_t)(b * Ss + s)) * Dd + h * HSs + c] = f2bf(v);
      }
}

// ---------------------------------------------------------------- GEMM2: out proj
// A = attnb [4096][1024] bf16, Bt = wpT [1024][1024] bf16, bias [1024], Out fp32 [4096][1024]
__global__ __launch_bounds__(256) void k_gemm_out(const unsigned short* __restrict__ A,
                                                  const unsigned short* __restrict__ Bt,
                                                  const float* __restrict__ bias,
                                                  float* __restrict__ Out) {
  __shared__ unsigned short As[128 * 64];
  __shared__ unsigned short Bs[128 * 64];
  const int K = 1024;
  int bid = blockIdx.x;
  int tm = bid / 8, tn = bid % 8;
  int m0 = tm * 128, n0 = tn * 128;
  int tid = threadIdx.x;
  int w = tid >> 6, l = tid & 63;
  int lr = l & 15, lg = l >> 4;
  int wm = (w >> 1) * 64, wn = (w & 1) * 64;
  int srow = l >> 3, scol = (l & 7) * 8;

  f32x4 acc[4][4];
  #pragma unroll
  for (int i = 0; i < 4; ++i)
    #pragma unroll
    for (int j = 0; j < 4; ++j)
      acc[i][j] = (f32x4){0.f, 0.f, 0.f, 0.f};

  for (int k0 = 0; k0 < K; k0 += 64) {
    #pragma unroll
    for (int c = 0; c < 4; ++c) {
      int chunk = w * 4 + c;
      int row = chunk * 8 + srow;
      async16(&A[(size_t)(m0 + row) * K + k0 + scol], &As[chunk * 512]);
      async16(&Bt[(size_t)(n0 + row) * K + k0 + scol], &Bs[chunk * 512]);
    }
    __syncthreads();
    #pragma unroll
    for (int kk = 0; kk < 64; kk += 32) {
      bf16x8 af[4], bfr[4];
      #pragma unroll
      for (int mf = 0; mf < 4; ++mf)
        af[mf] = *reinterpret_cast<const bf16x8*>(&As[(wm + mf * 16 + lr) * 64 + kk + lg * 8]);
      #pragma unroll
      for (int nf = 0; nf < 4; ++nf)
        bfr[nf] = *reinterpret_cast<const bf16x8*>(&Bs[(wn + nf * 16 + lr) * 64 + kk + lg * 8]);
      #pragma unroll
      for (int mf = 0; mf < 4; ++mf)
        #pragma unroll
        for (int nf = 0; nf < 4; ++nf)
          acc[mf][nf] = __builtin_amdgcn_mfma_f32_16x16x32_bf16(af[mf], bfr[nf], acc[mf][nf], 0, 0, 0);
    }
    __syncthreads();
  }

  #pragma unroll
  for (int mf = 0; mf < 4; ++mf)
    #pragma unroll
    for (int nf = 0; nf < 4; ++nf) {
      int n = n0 + wn + nf * 16 + lr;
      float bv = bias[n];
      #pragma unroll
      for (int j = 0; j < 4; ++j) {
        int m = m0 + wm + mf * 16 + lg * 4 + j;
        Out[(size_t)m * 1024 + n] = acc[mf][nf][j] + bv;
      }
    }
}

// ---------------------------------------------------------------- launch
extern "C" void kernel_launch(void* const* d_in, const int* in_sizes, int n_in,
                              void* d_out, int out_size, void* d_ws, size_t ws_size,
                              hipStream_t stream) {
  (void)in_sizes; (void)n_in; (void)out_size; (void)ws_size;
  const float* x      = (const float*)d_in[0];
  // d_in[1] = mask (exact causal tril) -- implemented directly
  const float* w_qkv  = (const float*)d_in[2];
  const float* b_qkv  = (const float*)d_in[3];
  const float* w_proj = (const float*)d_in[4];
  const float* b_proj = (const float*)d_in[5];
  float* out = (float*)d_out;

  char* ws = (char*)d_ws;
  unsigned short* xb    = (unsigned short*)(ws);              //  8 MB [4096][1024]
  unsigned short* wqkvT = (unsigned short*)(ws + 8388608);    //  6 MB [3072][1024]
  unsigned short* wpT   = (unsigned short*)(ws + 14680064);   //  2 MB [1024][1024]
  unsigned short* Qg    = (unsigned short*)(ws + 16777216);   //  8 MB [32][2048][64]
  unsigned short* Kg    = (unsigned short*)(ws + 25165824);   //  8 MB [32][2048][64]
  unsigned short* Vt    = (unsigned short*)(ws + 33554432);   //  8 MB [32][64][2048]
  unsigned short* attnb = (unsigned short*)(ws + 41943040);   //  8 MB [4096][1024]

  k_cvt_bf16<<<dim3(2048), dim3(256), 0, stream>>>(x, xb, Bb * Ss * Dd);
  k_transpose_bf16<<<dim3(96, 32), dim3(32, 8), 0, stream>>>(w_qkv, wqkvT, 1024, 3072);
  k_transpose_bf16<<<dim3(32, 32), dim3(32, 8), 0, stream>>>(w_proj, wpT, 1024, 1024);
  k_gemm_qkv<<<dim3(32 * 24), dim3(256), 0, stream>>>(xb, wqkvT, b_qkv, Qg, Kg, Vt);
  k_attn<<<dim3(512), dim3(256), 0, stream>>>(Qg, Kg, Vt, attnb);
  k_gemm_out<<<dim3(32 * 8), dim3(256), 0, stream>>>(attnb, wpT, b_proj, out);
}

// Round 2
// 256.516 us; speedup vs baseline: 1.1895x; 1.1895x over previous
//
#include <hip/hip_runtime.h>
#include <hip/hip_bf16.h>

// GPT-2 attention: B=2, S=2048, D=1024, H=16, HS=64
// Pipeline: cvt(x)->bf16 ; transpose(w_qkv), transpose(w_proj) -> [N][K] bf16 ;
//           GEMM1 (qkv proj, scatter Q/K/V per-head, Q scaled, V transposed) ;
//           flash attention (causal, online softmax, 64-row q-tiles, swizzled LDS) ;
//           GEMM2 (out proj, +bias, fp32 out).

#define Bb 2
#define Ss 2048
#define Dd 1024
#define Hh 16
#define HSs 64

typedef __bf16 bf16x8 __attribute__((ext_vector_type(8)));
typedef float  f32x4  __attribute__((ext_vector_type(4)));

__device__ __forceinline__ unsigned short f2bf(float f) {
  unsigned int u = __float_as_uint(f);
  unsigned int lsb = (u >> 16) & 1u;
  u += 0x7fffu + lsb;               // round-to-nearest-even (finite values)
  return (unsigned short)(u >> 16);
}

__device__ __forceinline__ void async16(const unsigned short* g, unsigned short* l) {
  __builtin_amdgcn_global_load_lds(
      (const __attribute__((address_space(1))) unsigned int*)g,
      (__attribute__((address_space(3))) unsigned int*)l,
      16, 0, 0);
}

// ---------------------------------------------------------------- cvt x -> bf16
__global__ __launch_bounds__(256) void k_cvt_bf16(const float* __restrict__ in,
                                                  unsigned short* __restrict__ out,
                                                  int n) {
  int i = (blockIdx.x * 256 + threadIdx.x) * 4;
  int stride = gridDim.x * 256 * 4;
  for (; i < n; i += stride) {
    float4 v = *reinterpret_cast<const float4*>(in + i);
    ushort4 o;
    o.x = f2bf(v.x); o.y = f2bf(v.y); o.z = f2bf(v.z); o.w = f2bf(v.w);
    *reinterpret_cast<ushort4*>(out + i) = o;
  }
}

// ------------------------------------------------- transpose f32 [R][C] -> bf16 [C][R]
__global__ __launch_bounds__(256) void k_transpose_bf16(const float* __restrict__ in,
                                                        unsigned short* __restrict__ out,
                                                        int R, int C) {
  __shared__ float t[32][33];
  int c0 = blockIdx.x * 32, r0 = blockIdx.y * 32;
  int tx = threadIdx.x, ty = threadIdx.y;  // block (32,8)
  #pragma unroll
  for (int i = 0; i < 32; i += 8)
    t[ty + i][tx] = in[(size_t)(r0 + ty + i) * C + (c0 + tx)];
  __syncthreads();
  #pragma unroll
  for (int i = 0; i < 32; i += 8)
    out[(size_t)(c0 + ty + i) * R + (r0 + tx)] = f2bf(t[tx][ty + i]);
}

// ---------------------------------------------------------------- GEMM1: QKV proj
__global__ __launch_bounds__(256) void k_gemm_qkv(const unsigned short* __restrict__ A,
                                                  const unsigned short* __restrict__ Bt,
                                                  const float* __restrict__ bias,
                                                  unsigned short* __restrict__ Qg,
                                                  unsigned short* __restrict__ Kg,
                                                  unsigned short* __restrict__ Vt) {
  __shared__ unsigned short As[128 * 64];
  __shared__ unsigned short Bs[128 * 64];
  const int K = 1024;
  int bid = blockIdx.x;
  int tm = bid / 24, tn = bid % 24;
  int m0 = tm * 128, n0 = tn * 128;
  int tid = threadIdx.x;
  int w = tid >> 6, l = tid & 63;
  int lr = l & 15, lg = l >> 4;
  int wm = (w >> 1) * 64, wn = (w & 1) * 64;
  int srow = l >> 3, scol = (l & 7) * 8;

  f32x4 acc[4][4];
  #pragma unroll
  for (int i = 0; i < 4; ++i)
    #pragma unroll
    for (int j = 0; j < 4; ++j)
      acc[i][j] = (f32x4){0.f, 0.f, 0.f, 0.f};

  for (int k0 = 0; k0 < K; k0 += 64) {
    #pragma unroll
    for (int c = 0; c < 4; ++c) {
      int chunk = w * 4 + c;
      int row = chunk * 8 + srow;
      async16(&A[(size_t)(m0 + row) * K + k0 + scol], &As[chunk * 512]);
      async16(&Bt[(size_t)(n0 + row) * K + k0 + scol], &Bs[chunk * 512]);
    }
    __syncthreads();
    #pragma unroll
    for (int kk = 0; kk < 64; kk += 32) {
      bf16x8 af[4], bfr[4];
      #pragma unroll
      for (int mf = 0; mf < 4; ++mf)
        af[mf] = *reinterpret_cast<const bf16x8*>(&As[(wm + mf * 16 + lr) * 64 + kk + lg * 8]);
      #pragma unroll
      for (int nf = 0; nf < 4; ++nf)
        bfr[nf] = *reinterpret_cast<const bf16x8*>(&Bs[(wn + nf * 16 + lr) * 64 + kk + lg * 8]);
      #pragma unroll
      for (int mf = 0; mf < 4; ++mf)
        #pragma unroll
        for (int nf = 0; nf < 4; ++nf)
          acc[mf][nf] = __builtin_amdgcn_mfma_f32_16x16x32_bf16(af[mf], bfr[nf], acc[mf][nf], 0, 0, 0);
    }
    __syncthreads();
  }

  #pragma unroll
  for (int mf = 0; mf < 4; ++mf) {
    #pragma unroll
    for (int nf = 0; nf < 4; ++nf) {
      int n = n0 + wn + nf * 16 + lr;
      int t = n >> 10, r = n & 1023;
      int h = r >> 6, cc = r & 63;
      float bv = bias[n];
      if (t == 2) {
        int m = m0 + wm + mf * 16 + lg * 4;
        int b = m >> 11, s = m & 2047;
        ushort4 pk;
        pk.x = f2bf(acc[mf][nf][0] + bv);
        pk.y = f2bf(acc[mf][nf][1] + bv);
        pk.z = f2bf(acc[mf][nf][2] + bv);
        pk.w = f2bf(acc[mf][nf][3] + bv);
        *reinterpret_cast<ushort4*>(&Vt[((size_t)(b * Hh + h) * HSs + cc) * Ss + s]) = pk;
      } else {
        #pragma unroll
        for (int j = 0; j < 4; ++j) {
          int m = m0 + wm + mf * 16 + lg * 4 + j;
          int b = m >> 11, s = m & 2047;
          size_t idx = ((size_t)(b * Hh + h) * Ss + s) * HSs + cc;
          float v = acc[mf][nf][j] + bv;
          if (t == 0) Qg[idx] = f2bf(v * 0.125f);
          else        Kg[idx] = f2bf(v);
        }
      }
    }
  }
}

// ---------------------------------------------------------------- flash attention
// grid 1024: bid = idx*32 + slot*8 + xcd ; bh = (idx&3)*8+xcd ; qt balanced over (idx>>2, slot).
// Block: 4 waves x 16 q-rows (64-row q-tile). KV tiles of 64. K/V LDS XOR-swizzled.
__global__ __launch_bounds__(256, 4) void k_attn(const unsigned short* __restrict__ Qg,
                                                 const unsigned short* __restrict__ Kg,
                                                 const unsigned short* __restrict__ Vt,
                                                 unsigned short* __restrict__ Ob) {
  __shared__ unsigned short Ks[64 * 64];
  __shared__ unsigned short Vs[64 * 64];
  __shared__ unsigned short Ps[4][16 * 72];

  int bid = blockIdx.x;
  int xcd = bid & 7, slot = (bid >> 3) & 3, idx = bid >> 5;
  int bh = (idx & 3) * 8 + xcd;
  int base = (idx >> 2) * 2 + (slot & 1);
  int qt = (slot & 2) ? 31 - base : base;    // 4 co-resident blocks: work sums constant
  int b = bh >> 4, h = bh & 15;
  int qs0 = qt * 64;

  int tid = threadIdx.x;
  int w = tid >> 6, l = tid & 63;
  int lr = l & 15, lg = l >> 4;
  int qw = qs0 + w * 16;
  int srow = l >> 3, scol = (l & 7) * 8;
  int swcol = scol ^ (srow << 3);            // pre-swizzled global source column

  // Q fragments: rows qw+lr, cols kx*32 + lg*8
  bf16x8 qf[2];
  #pragma unroll
  for (int kx = 0; kx < 2; ++kx)
    qf[kx] = *reinterpret_cast<const bf16x8*>(
        &Qg[((size_t)bh * Ss + qw + lr) * HSs + kx * 32 + lg * 8]);

  f32x4 oacc[4];
  #pragma unroll
  for (int nf = 0; nf < 4; ++nf) oacc[nf] = (f32x4){0.f, 0.f, 0.f, 0.f};
  float mrun[4], lrun[4];
  #pragma unroll
  for (int j = 0; j < 4; ++j) { mrun[j] = -1e30f; lrun[j] = 0.f; }

  int ntiles = qt + 1;
  for (int t = 0; t < ntiles; ++t) {
    #pragma unroll
    for (int cch = 0; cch < 2; ++cch) {
      int chunk = w * 2 + cch;
      int row = chunk * 8 + srow;
      async16(&Kg[((size_t)bh * Ss + t * 64 + row) * HSs + swcol], &Ks[chunk * 512]);
      async16(&Vt[((size_t)bh * HSs + row) * Ss + t * 64 + swcol], &Vs[chunk * 512]);
    }
    __syncthreads();

    // QK^T
    f32x4 sacc[4];
    #pragma unroll
    for (int nf = 0; nf < 4; ++nf) sacc[nf] = (f32x4){0.f, 0.f, 0.f, 0.f};
    #pragma unroll
    for (int kx = 0; kx < 2; ++kx) {
      bf16x8 kf[4];
      #pragma unroll
      for (int nf = 0; nf < 4; ++nf)
        kf[nf] = *reinterpret_cast<const bf16x8*>(
            &Ks[(nf * 16 + lr) * 64 + ((kx * 32 + lg * 8) ^ ((lr & 7) << 3))]);
      #pragma unroll
      for (int nf = 0; nf < 4; ++nf)
        sacc[nf] = __builtin_amdgcn_mfma_f32_16x16x32_bf16(qf[kx], kf[nf], sacc[nf], 0, 0, 0);
    }

    if (t == ntiles - 1) {  // diagonal tile: causal mask
      #pragma unroll
      for (int nf = 0; nf < 4; ++nf) {
        int kcol = qs0 + nf * 16 + lr;
        #pragma unroll
        for (int j = 0; j < 4; ++j) {
          int qg = qw + lg * 4 + j;
          if (kcol > qg) sacc[nf][j] = -1e30f;
        }
      }
    }

    // online softmax (row = lg*4+j, cols = nf*16+lr)
    #pragma unroll
    for (int j = 0; j < 4; ++j) {
      float rmax = fmaxf(fmaxf(sacc[0][j], sacc[1][j]), fmaxf(sacc[2][j], sacc[3][j]));
      #pragma unroll
      for (int d = 1; d < 16; d <<= 1)
        rmax = fmaxf(rmax, __shfl_xor(rmax, d));
      float mnew = fmaxf(mrun[j], rmax);
      float cf = __expf(mrun[j] - mnew);
      mrun[j] = mnew;
      float psum = 0.f;
      #pragma unroll
      for (int nf = 0; nf < 4; ++nf) {
        float p = __expf(sacc[nf][j] - mnew);
        sacc[nf][j] = p;
        psum += p;
      }
      #pragma unroll
      for (int d = 1; d < 16; d <<= 1)
        psum += __shfl_xor(psum, d);
      lrun[j] = lrun[j] * cf + psum;
      #pragma unroll
      for (int nf = 0; nf < 4; ++nf)
        oacc[nf][j] *= cf;
    }

    // P -> LDS (per-wave, padded stride 72)
    #pragma unroll
    for (int nf = 0; nf < 4; ++nf)
      #pragma unroll
      for (int j = 0; j < 4; ++j)
        Ps[w][(lg * 4 + j) * 72 + nf * 16 + lr] = f2bf(sacc[nf][j]);

    // PV
    #pragma unroll
    for (int kx = 0; kx < 2; ++kx) {
      bf16x8 pf = *reinterpret_cast<const bf16x8*>(&Ps[w][lr * 72 + kx * 32 + lg * 8]);
      bf16x8 vf[4];
      #pragma unroll
      for (int nf = 0; nf < 4; ++nf)
        vf[nf] = *reinterpret_cast<const bf16x8*>(
            &Vs[(nf * 16 + lr) * 64 + ((kx * 32 + lg * 8) ^ ((lr & 7) << 3))]);
      #pragma unroll
      for (int nf = 0; nf < 4; ++nf)
        oacc[nf] = __builtin_amdgcn_mfma_f32_16x16x32_bf16(pf, vf[nf], oacc[nf], 0, 0, 0);
    }
    __syncthreads();
  }

  #pragma unroll
  for (int j = 0; j < 4; ++j) {
    float rinv = 1.0f / lrun[j];
    int s = qw + lg * 4 + j;
    #pragma unroll
    for (int nf = 0; nf < 4; ++nf) {
      int c = nf * 16 + lr;
      Ob[((size_t)(b * Ss + s)) * Dd + h * HSs + c] = f2bf(oacc[nf][j] * rinv);
    }
  }
}

// ---------------------------------------------------------------- GEMM2: out proj
__global__ __launch_bounds__(256) void k_gemm_out(const unsigned short* __restrict__ A,
                                                  const unsigned short* __restrict__ Bt,
                                                  const float* __restrict__ bias,
                                                  float* __restrict__ Out) {
  __shared__ unsigned short As[128 * 64];
  __shared__ unsigned short Bs[128 * 64];
  const int K = 1024;
  int bid = blockIdx.x;
  int tm = bid / 8, tn = bid % 8;
  int m0 = tm * 128, n0 = tn * 128;
  int tid = threadIdx.x;
  int w = tid >> 6, l = tid & 63;
  int lr = l & 15, lg = l >> 4;
  int wm = (w >> 1) * 64, wn = (w & 1) * 64;
  int srow = l >> 3, scol = (l & 7) * 8;

  f32x4 acc[4][4];
  #pragma unroll
  for (int i = 0; i < 4; ++i)
    #pragma unroll
    for (int j = 0; j < 4; ++j)
      acc[i][j] = (f32x4){0.f, 0.f, 0.f, 0.f};

  for (int k0 = 0; k0 < K; k0 += 64) {
    #pragma unroll
    for (int c = 0; c < 4; ++c) {
      int chunk = w * 4 + c;
      int row = chunk * 8 + srow;
      async16(&A[(size_t)(m0 + row) * K + k0 + scol], &As[chunk * 512]);
      async16(&Bt[(size_t)(n0 + row) * K + k0 + scol], &Bs[chunk * 512]);
    }
    __syncthreads();
    #pragma unroll
    for (int kk = 0; kk < 64; kk += 32) {
      bf16x8 af[4], bfr[4];
      #pragma unroll
      for (int mf = 0; mf < 4; ++mf)
        af[mf] = *reinterpret_cast<const bf16x8*>(&As[(wm + mf * 16 + lr) * 64 + kk + lg * 8]);
      #pragma unroll
      for (int nf = 0; nf < 4; ++nf)
        bfr[nf] = *reinterpret_cast<const bf16x8*>(&Bs[(wn + nf * 16 + lr) * 64 + kk + lg * 8]);
      #pragma unroll
      for (int mf = 0; mf < 4; ++mf)
        #pragma unroll
        for (int nf = 0; nf < 4; ++nf)
          acc[mf][nf] = __builtin_amdgcn_mfma_f32_16x16x32_bf16(af[mf], bfr[nf], acc[mf][nf], 0, 0, 0);
    }
    __syncthreads();
  }

  #pragma unroll
  for (int mf = 0; mf < 4; ++mf)
    #pragma unroll
    for (int nf = 0; nf < 4; ++nf) {
      int n = n0 + wn + nf * 16 + lr;
      float bv = bias[n];
      #pragma unroll
      for (int j = 0; j < 4; ++j) {
        int m = m0 + wm + mf * 16 + lg * 4 + j;
        Out[(size_t)m * 1024 + n] = acc[mf][nf][j] + bv;
      }
    }
}

// ---------------------------------------------------------------- launch
extern "C" void kernel_launch(void* const* d_in, const int* in_sizes, int n_in,
                              void* d_out, int out_size, void* d_ws, size_t ws_size,
                              hipStream_t stream) {
  (void)in_sizes; (void)n_in; (void)out_size; (void)ws_size;
  const float* x      = (const float*)d_in[0];
  const float* w_qkv  = (const float*)d_in[2];
  const float* b_qkv  = (const float*)d_in[3];
  const float* w_proj = (const float*)d_in[4];
  const float* b_proj = (const float*)d_in[5];
  float* out = (float*)d_out;

  char* ws = (char*)d_ws;
  unsigned short* xb    = (unsigned short*)(ws);              //  8 MB [4096][1024]
  unsigned short* wqkvT = (unsigned short*)(ws + 8388608);    //  6 MB [3072][1024]
  unsigned short* wpT   = (unsigned short*)(ws + 14680064);   //  2 MB [1024][1024]
  unsigned short* Qg    = (unsigned short*)(ws + 16777216);   //  8 MB [32][2048][64]
  unsigned short* Kg    = (unsigned short*)(ws + 25165824);   //  8 MB [32][2048][64]
  unsigned short* Vt    = (unsigned short*)(ws + 33554432);   //  8 MB [32][64][2048]
  unsigned short* attnb = (unsigned short*)(ws + 41943040);   //  8 MB [4096][1024]

  k_cvt_bf16<<<dim3(2048), dim3(256), 0, stream>>>(x, xb, Bb * Ss * Dd);
  k_transpose_bf16<<<dim3(96, 32), dim3(32, 8), 0, stream>>>(w_qkv, wqkvT, 1024, 3072);
  k_transpose_bf16<<<dim3(32, 32), dim3(32, 8), 0, stream>>>(w_proj, wpT, 1024, 1024);
  k_gemm_qkv<<<dim3(32 * 24), dim3(256), 0, stream>>>(xb, wqkvT, b_qkv, Qg, Kg, Vt);
  k_attn<<<dim3(1024), dim3(256), 0, stream>>>(Qg, Kg, Vt, attnb);
  k_gemm_out<<<dim3(32 * 8), dim3(256), 0, stream>>>(attnb, wpT, b_proj, out);
}

// Round 3
// 237.104 us; speedup vs baseline: 1.2869x; 1.0819x over previous
//
#include <hip/hip_runtime.h>
#include <hip/hip_bf16.h>

// GPT-2 attention: B=2, S=2048, D=1024, H=16, HS=64
// cvt(x)->bf16 ; transpose weights -> [N][K] bf16 ; GEMM1 (QKV proj, scatter, Q scaled,
// V transposed) ; flash attention (paired q-tiles, double-buffered KV, swizzled LDS) ;
// GEMM2 (out proj, +bias, fp32 out).

#define Bb 2
#define Ss 2048
#define Dd 1024
#define Hh 16
#define HSs 64

typedef __bf16 bf16x8 __attribute__((ext_vector_type(8)));
typedef float  f32x4  __attribute__((ext_vector_type(4)));

__device__ __forceinline__ unsigned short f2bf(float f) {
  unsigned int u = __float_as_uint(f);
  unsigned int lsb = (u >> 16) & 1u;
  u += 0x7fffu + lsb;               // round-to-nearest-even (finite values)
  return (unsigned short)(u >> 16);
}

__device__ __forceinline__ void async16(const unsigned short* g, unsigned short* l) {
  __builtin_amdgcn_global_load_lds(
      (const __attribute__((address_space(1))) unsigned int*)g,
      (__attribute__((address_space(3))) unsigned int*)l,
      16, 0, 0);
}

// ---------------------------------------------------------------- cvt x -> bf16
__global__ __launch_bounds__(256) void k_cvt_bf16(const float* __restrict__ in,
                                                  unsigned short* __restrict__ out,
                                                  int n) {
  int i = (blockIdx.x * 256 + threadIdx.x) * 4;
  int stride = gridDim.x * 256 * 4;
  for (; i < n; i += stride) {
    float4 v = *reinterpret_cast<const float4*>(in + i);
    ushort4 o;
    o.x = f2bf(v.x); o.y = f2bf(v.y); o.z = f2bf(v.z); o.w = f2bf(v.w);
    *reinterpret_cast<ushort4*>(out + i) = o;
  }
}

// ------------------------------------------------- transpose f32 [R][C] -> bf16 [C][R]
__global__ __launch_bounds__(256) void k_transpose_bf16(const float* __restrict__ in,
                                                        unsigned short* __restrict__ out,
                                                        int R, int C) {
  __shared__ float t[32][33];
  int c0 = blockIdx.x * 32, r0 = blockIdx.y * 32;
  int tx = threadIdx.x, ty = threadIdx.y;  // block (32,8)
  #pragma unroll
  for (int i = 0; i < 32; i += 8)
    t[ty + i][tx] = in[(size_t)(r0 + ty + i) * C + (c0 + tx)];
  __syncthreads();
  #pragma unroll
  for (int i = 0; i < 32; i += 8)
    out[(size_t)(c0 + ty + i) * R + (r0 + tx)] = f2bf(t[tx][ty + i]);
}

// ---------------------------------------------------------------- GEMM1: QKV proj
__global__ __launch_bounds__(256) void k_gemm_qkv(const unsigned short* __restrict__ A,
                                                  const unsigned short* __restrict__ Bt,
                                                  const float* __restrict__ bias,
                                                  unsigned short* __restrict__ Qg,
                                                  unsigned short* __restrict__ Kg,
                                                  unsigned short* __restrict__ Vt) {
  __shared__ unsigned short As[128 * 64];
  __shared__ unsigned short Bs[128 * 64];
  const int K = 1024;
  int bid = blockIdx.x;
  int swz = (bid % 8) * 96 + bid / 8;        // XCD-contiguous: 4 m-panels per XCD
  int tm = swz / 24, tn = swz % 24;
  int m0 = tm * 128, n0 = tn * 128;
  int tid = threadIdx.x;
  int w = tid >> 6, l = tid & 63;
  int lr = l & 15, lg = l >> 4;
  int wm = (w >> 1) * 64, wn = (w & 1) * 64;
  int srow = l >> 3, scol = (l & 7) * 8;

  f32x4 acc[4][4];
  #pragma unroll
  for (int i = 0; i < 4; ++i)
    #pragma unroll
    for (int j = 0; j < 4; ++j)
      acc[i][j] = (f32x4){0.f, 0.f, 0.f, 0.f};

  for (int k0 = 0; k0 < K; k0 += 64) {
    #pragma unroll
    for (int c = 0; c < 4; ++c) {
      int chunk = w * 4 + c;
      int row = chunk * 8 + srow;
      async16(&A[(size_t)(m0 + row) * K + k0 + scol], &As[chunk * 512]);
      async16(&Bt[(size_t)(n0 + row) * K + k0 + scol], &Bs[chunk * 512]);
    }
    __syncthreads();
    #pragma unroll
    for (int kk = 0; kk < 64; kk += 32) {
      bf16x8 af[4], bfr[4];
      #pragma unroll
      for (int mf = 0; mf < 4; ++mf)
        af[mf] = *reinterpret_cast<const bf16x8*>(&As[(wm + mf * 16 + lr) * 64 + kk + lg * 8]);
      #pragma unroll
      for (int nf = 0; nf < 4; ++nf)
        bfr[nf] = *reinterpret_cast<const bf16x8*>(&Bs[(wn + nf * 16 + lr) * 64 + kk + lg * 8]);
      #pragma unroll
      for (int mf = 0; mf < 4; ++mf)
        #pragma unroll
        for (int nf = 0; nf < 4; ++nf)
          acc[mf][nf] = __builtin_amdgcn_mfma_f32_16x16x32_bf16(af[mf], bfr[nf], acc[mf][nf], 0, 0, 0);
    }
    __syncthreads();
  }

  #pragma unroll
  for (int mf = 0; mf < 4; ++mf) {
    #pragma unroll
    for (int nf = 0; nf < 4; ++nf) {
      int n = n0 + wn + nf * 16 + lr;
      int t = n >> 10, r = n & 1023;
      int h = r >> 6, cc = r & 63;
      float bv = bias[n];
      if (t == 2) {
        int m = m0 + wm + mf * 16 + lg * 4;
        int b = m >> 11, s = m & 2047;
        ushort4 pk;
        pk.x = f2bf(acc[mf][nf][0] + bv);
        pk.y = f2bf(acc[mf][nf][1] + bv);
        pk.z = f2bf(acc[mf][nf][2] + bv);
        pk.w = f2bf(acc[mf][nf][3] + bv);
        *reinterpret_cast<ushort4*>(&Vt[((size_t)(b * Hh + h) * HSs + cc) * Ss + s]) = pk;
      } else {
        #pragma unroll
        for (int j = 0; j < 4; ++j) {
          int m = m0 + wm + mf * 16 + lg * 4 + j;
          int b = m >> 11, s = m & 2047;
          size_t idx = ((size_t)(b * Hh + h) * Ss + s) * HSs + cc;
          float v = acc[mf][nf][j] + bv;
          if (t == 0) Qg[idx] = f2bf(v * 0.125f);
          else        Kg[idx] = f2bf(v);
        }
      }
    }
  }
}

// ---------------------------------------------------------------- flash attention
// grid 512: bid = p*32 + bh, p in 0..15. 512 threads = 8 waves.
// Waves 0-3: q-tile p ; waves 4-7: q-tile 31-p (each wave 16 q rows).
// Compute per block = (p+1)+(32-p) = 33 tile-works, perfectly balanced.
// K/V staged once for union range, double-buffered, XOR-swizzled. 1 barrier/tile.
__global__ __launch_bounds__(512, 4) void k_attn(const unsigned short* __restrict__ Qg,
                                                 const unsigned short* __restrict__ Kg,
                                                 const unsigned short* __restrict__ Vt,
                                                 unsigned short* __restrict__ Ob) {
  __shared__ unsigned short Ks[2][64 * 64];
  __shared__ unsigned short Vs[2][64 * 64];
  __shared__ unsigned short Ps[8][16 * 72];

  int bid = blockIdx.x;
  int p  = bid >> 5;          // pair index 0..15
  int bh = bid & 31;          // co-resident blocks (bid +/- 256) share bh -> L2 reuse
  int b = bh >> 4, h = bh & 15;

  int tid = threadIdx.x;
  int w = tid >> 6, l = tid & 63;
  int g = w >> 2;                         // 0: qt=p, 1: qt=31-p
  int myqt = g ? (31 - p) : p;
  int qs0 = myqt * 64;
  int lr = l & 15, lg = l >> 4;
  int qw = qs0 + (w & 3) * 16;
  int srow = l >> 3, scol = (l & 7) * 8;
  int swcol = scol ^ (srow << 3);         // pre-swizzled global source column

  // Q fragments: rows qw+lr, cols kx*32 + lg*8
  bf16x8 qf[2];
  #pragma unroll
  for (int kx = 0; kx < 2; ++kx)
    qf[kx] = *reinterpret_cast<const bf16x8*>(
        &Qg[((size_t)bh * Ss + qw + lr) * HSs + kx * 32 + lg * 8]);

  f32x4 oacc[4];
  #pragma unroll
  for (int nf = 0; nf < 4; ++nf) oacc[nf] = (f32x4){0.f, 0.f, 0.f, 0.f};
  float mrun[4], lrun[4];
  #pragma unroll
  for (int j = 0; j < 4; ++j) { mrun[j] = -1e30f; lrun[j] = 0.f; }

  // staging: wave w loads K chunk w (rows w*8..w*8+7) and V chunk w, 1 KiB each
  int ntiles = 32 - p;
  {
    int row = w * 8 + srow;
    async16(&Kg[((size_t)bh * Ss + 0 * 64 + row) * HSs + swcol], &Ks[0][w * 512]);
    async16(&Vt[((size_t)bh * HSs + row) * Ss + 0 * 64 + swcol], &Vs[0][w * 512]);
  }
  __syncthreads();

  for (int t = 0; t < ntiles; ++t) {
    int cur = t & 1;
    if (t + 1 < ntiles) {                 // issue next-tile stage BEFORE compute
      int row = w * 8 + srow;
      async16(&Kg[((size_t)bh * Ss + (t + 1) * 64 + row) * HSs + swcol], &Ks[cur ^ 1][w * 512]);
      async16(&Vt[((size_t)bh * HSs + row) * Ss + (t + 1) * 64 + swcol], &Vs[cur ^ 1][w * 512]);
    }

    if (t <= myqt) {
      // QK^T
      f32x4 sacc[4];
      #pragma unroll
      for (int nf = 0; nf < 4; ++nf) sacc[nf] = (f32x4){0.f, 0.f, 0.f, 0.f};
      #pragma unroll
      for (int kx = 0; kx < 2; ++kx) {
        bf16x8 kf[4];
        #pragma unroll
        for (int nf = 0; nf < 4; ++nf)
          kf[nf] = *reinterpret_cast<const bf16x8*>(
              &Ks[cur][(nf * 16 + lr) * 64 + ((kx * 32 + lg * 8) ^ ((lr & 7) << 3))]);
        #pragma unroll
        for (int nf = 0; nf < 4; ++nf)
          sacc[nf] = __builtin_amdgcn_mfma_f32_16x16x32_bf16(qf[kx], kf[nf], sacc[nf], 0, 0, 0);
      }

      if (t == myqt) {  // diagonal tile: causal mask
        #pragma unroll
        for (int nf = 0; nf < 4; ++nf) {
          int kcol = qs0 + nf * 16 + lr;
          #pragma unroll
          for (int j = 0; j < 4; ++j) {
            int qg2 = qw + lg * 4 + j;
            if (kcol > qg2) sacc[nf][j] = -1e30f;
          }
        }
      }

      // online softmax (row = lg*4+j, cols = nf*16+lr)
      #pragma unroll
      for (int j = 0; j < 4; ++j) {
        float rmax = fmaxf(fmaxf(sacc[0][j], sacc[1][j]), fmaxf(sacc[2][j], sacc[3][j]));
        #pragma unroll
        for (int d = 1; d < 16; d <<= 1)
          rmax = fmaxf(rmax, __shfl_xor(rmax, d));
        float mnew = fmaxf(mrun[j], rmax);
        float cf = __expf(mrun[j] - mnew);
        mrun[j] = mnew;
        float psum = 0.f;
        #pragma unroll
        for (int nf = 0; nf < 4; ++nf) {
          float pv = __expf(sacc[nf][j] - mnew);
          sacc[nf][j] = pv;
          psum += pv;
        }
        #pragma unroll
        for (int d = 1; d < 16; d <<= 1)
          psum += __shfl_xor(psum, d);
        lrun[j] = lrun[j] * cf + psum;
        #pragma unroll
        for (int nf = 0; nf < 4; ++nf)
          oacc[nf][j] *= cf;
      }

      // P -> LDS (per-wave, padded stride 72)
      #pragma unroll
      for (int nf = 0; nf < 4; ++nf)
        #pragma unroll
        for (int j = 0; j < 4; ++j)
          Ps[w][(lg * 4 + j) * 72 + nf * 16 + lr] = f2bf(sacc[nf][j]);

      // PV
      #pragma unroll
      for (int kx = 0; kx < 2; ++kx) {
        bf16x8 pf = *reinterpret_cast<const bf16x8*>(&Ps[w][lr * 72 + kx * 32 + lg * 8]);
        bf16x8 vf[4];
        #pragma unroll
        for (int nf = 0; nf < 4; ++nf)
          vf[nf] = *reinterpret_cast<const bf16x8*>(
              &Vs[cur][(nf * 16 + lr) * 64 + ((kx * 32 + lg * 8) ^ ((lr & 7) << 3))]);
        #pragma unroll
        for (int nf = 0; nf < 4; ++nf)
          oacc[nf] = __builtin_amdgcn_mfma_f32_16x16x32_bf16(pf, vf[nf], oacc[nf], 0, 0, 0);
      }
    }
    __syncthreads();   // drains this iter's ds_reads + next-tile vmcnt
  }

  #pragma unroll
  for (int j = 0; j < 4; ++j) {
    float rinv = 1.0f / lrun[j];
    int s = qw + lg * 4 + j;
    #pragma unroll
    for (int nf = 0; nf < 4; ++nf) {
      int c = nf * 16 + lr;
      Ob[((size_t)(b * Ss + s)) * Dd + h * HSs + c] = f2bf(oacc[nf][j] * rinv);
    }
  }
}

// ---------------------------------------------------------------- GEMM2: out proj
__global__ __launch_bounds__(256) void k_gemm_out(const unsigned short* __restrict__ A,
                                                  const unsigned short* __restrict__ Bt,
                                                  const float* __restrict__ bias,
                                                  float* __restrict__ Out) {
  __shared__ unsigned short As[128 * 64];
  __shared__ unsigned short Bs[128 * 64];
  const int K = 1024;
  int bid = blockIdx.x;
  int swz = (bid % 8) * 32 + bid / 8;       // XCD-contiguous
  int tm = swz / 8, tn = swz % 8;
  int m0 = tm * 128, n0 = tn * 128;
  int tid = threadIdx.x;
  int w = tid >> 6, l = tid & 63;
  int lr = l & 15, lg = l >> 4;
  int wm = (w >> 1) * 64, wn = (w & 1) * 64;
  int srow = l >> 3, scol = (l & 7) * 8;

  f32x4 acc[4][4];
  #pragma unroll
  for (int i = 0; i < 4; ++i)
    #pragma unroll
    for (int j = 0; j < 4; ++j)
      acc[i][j] = (f32x4){0.f, 0.f, 0.f, 0.f};

  for (int k0 = 0; k0 < K; k0 += 64) {
    #pragma unroll
    for (int c = 0; c < 4; ++c) {
      int chunk = w * 4 + c;
      int row = chunk * 8 + srow;
      async16(&A[(size_t)(m0 + row) * K + k0 + scol], &As[chunk * 512]);
      async16(&Bt[(size_t)(n0 + row) * K + k0 + scol], &Bs[chunk * 512]);
    }
    __syncthreads();
    #pragma unroll
    for (int kk = 0; kk < 64; kk += 32) {
      bf16x8 af[4], bfr[4];
      #pragma unroll
      for (int mf = 0; mf < 4; ++mf)
        af[mf] = *reinterpret_cast<const bf16x8*>(&As[(wm + mf * 16 + lr) * 64 + kk + lg * 8]);
      #pragma unroll
      for (int nf = 0; nf < 4; ++nf)
        bfr[nf] = *reinterpret_cast<const bf16x8*>(&Bs[(wn + nf * 16 + lr) * 64 + kk + lg * 8]);
      #pragma unroll
      for (int mf = 0; mf < 4; ++mf)
        #pragma unroll
        for (int nf = 0; nf < 4; ++nf)
          acc[mf][nf] = __builtin_amdgcn_mfma_f32_16x16x32_bf16(af[mf], bfr[nf], acc[mf][nf], 0, 0, 0);
    }
    __syncthreads();
  }

  #pragma unroll
  for (int mf = 0; mf < 4; ++mf)
    #pragma unroll
    for (int nf = 0; nf < 4; ++nf) {
      int n = n0 + wn + nf * 16 + lr;
      float bv = bias[n];
      #pragma unroll
      for (int j = 0; j < 4; ++j) {
        int m = m0 + wm + mf * 16 + lg * 4 + j;
        Out[(size_t)m * 1024 + n] = acc[mf][nf][j] + bv;
      }
    }
}

// ---------------------------------------------------------------- launch
extern "C" void kernel_launch(void* const* d_in, const int* in_sizes, int n_in,
                              void* d_out, int out_size, void* d_ws, size_t ws_size,
                              hipStream_t stream) {
  (void)in_sizes; (void)n_in; (void)out_size; (void)ws_size;
  const float* x      = (const float*)d_in[0];
  const float* w_qkv  = (const float*)d_in[2];
  const float* b_qkv  = (const float*)d_in[3];
  const float* w_proj = (const float*)d_in[4];
  const float* b_proj = (const float*)d_in[5];
  float* out = (float*)d_out;

  char* ws = (char*)d_ws;
  unsigned short* xb    = (unsigned short*)(ws);              //  8 MB [4096][1024]
  unsigned short* wqkvT = (unsigned short*)(ws + 8388608);    //  6 MB [3072][1024]
  unsigned short* wpT   = (unsigned short*)(ws + 14680064);   //  2 MB [1024][1024]
  unsigned short* Qg    = (unsigned short*)(ws + 16777216);   //  8 MB [32][2048][64]
  unsigned short* Kg    = (unsigned short*)(ws + 25165824);   //  8 MB [32][2048][64]
  unsigned short* Vt    = (unsigned short*)(ws + 33554432);   //  8 MB [32][64][2048]
  unsigned short* attnb = (unsigned short*)(ws + 41943040);   //  8 MB [4096][1024]

  k_cvt_bf16<<<dim3(2048), dim3(256), 0, stream>>>(x, xb, Bb * Ss * Dd);
  k_transpose_bf16<<<dim3(96, 32), dim3(32, 8), 0, stream>>>(w_qkv, wqkvT, 1024, 3072);
  k_transpose_bf16<<<dim3(32, 32), dim3(32, 8), 0, stream>>>(w_proj, wpT, 1024, 1024);
  k_gemm_qkv<<<dim3(32 * 24), dim3(256), 0, stream>>>(xb, wqkvT, b_qkv, Qg, Kg, Vt);
  k_attn<<<dim3(512), dim3(512), 0, stream>>>(Qg, Kg, Vt, attnb);
  k_gemm_out<<<dim3(32 * 8), dim3(256), 0, stream>>>(attnb, wpT, b_proj, out);
}